// Round 1
// baseline (140.204 us; speedup 1.0000x reference)
//
#include <hip/hip_runtime.h>
#include <hip/hip_bf16.h>

// Problem constants
#define B_   32
#define N_   128
#define KNB  16
#define C_   1024
#define KER  8
#define DOUT 128      // OUT/KERNEL
#define OUTC 1024
#define BN_TOT (B_ * N_)   // 4096

typedef __attribute__((ext_vector_type(8))) short bf16x8;
typedef __attribute__((ext_vector_type(4))) float f32x4;

__device__ __forceinline__ ushort f2bf(float f) {
    unsigned u = __builtin_bit_cast(unsigned, f);
    unsigned r = (u + 0x7FFFu + ((u >> 16) & 1u)) >> 16;
    return (ushort)r;
}

#define GLOAD_LDS16(gp, lp)                                                    \
    __builtin_amdgcn_global_load_lds(                                          \
        (__attribute__((address_space(1))) void*)(gp),                         \
        (__attribute__((address_space(3))) void*)(lp), 16, 0, 0)

// ---------------------------------------------------------------------------
// Kernel 1: node_feats f32 [4096][1024] -> bf16 Fb [4096][1024]
// ---------------------------------------------------------------------------
__global__ __launch_bounds__(256) void k_convert_f(const float* __restrict__ f,
                                                   ushort* __restrict__ Fb) {
    int t = blockIdx.x * 256 + threadIdx.x;      // 1,048,576 threads, 4 elems each
    float4 v = ((const float4*)f)[t];
    ushort4 o;
    o.x = f2bf(v.x); o.y = f2bf(v.y); o.z = f2bf(v.z); o.w = f2bf(v.w);
    ((ushort4*)Fb)[t] = o;
}

// ---------------------------------------------------------------------------
// Kernel 2: conv_w f32 [KER][C][DOUT] -> WbT bf16 [KER*DOUT][C]
//           WbT[m*128+d][c] = conv_w[m][c][d]   (tiled 32x32 transpose via LDS)
// ---------------------------------------------------------------------------
__global__ __launch_bounds__(256) void k_transpose_w(const float* __restrict__ cw,
                                                     ushort* __restrict__ WbT) {
    __shared__ float tile[32][33];
    int bid = blockIdx.x;            // 8 * 32 * 4 = 1024 blocks
    int dt = bid & 3;                // d-tile (128/32)
    int ct = (bid >> 2) & 31;        // c-tile (1024/32)
    int m  = bid >> 7;
    int tx = threadIdx.x & 31;
    int ty = threadIdx.x >> 5;       // 0..7
#pragma unroll
    for (int i = 0; i < 4; ++i) {
        int cr = ty + i * 8;
        tile[cr][tx] = cw[((size_t)m * C_ + (ct * 32 + cr)) * DOUT + dt * 32 + tx];
    }
    __syncthreads();
#pragma unroll
    for (int i = 0; i < 4; ++i) {
        int dr = ty + i * 8;
        WbT[((size_t)(m * DOUT + dt * 32 + dr)) * C_ + ct * 32 + tx] = f2bf(tile[tx][dr]);
    }
}

// ---------------------------------------------------------------------------
// Kernel 3: edge weights ew[b][n][k][m] f32
// ---------------------------------------------------------------------------
__global__ __launch_bounds__(256) void k_edgew(const float* __restrict__ centre,
                                               const int* __restrict__ nidx,
                                               const float* __restrict__ gw,
                                               const float* __restrict__ mr,
                                               const float* __restrict__ mt,
                                               const float* __restrict__ pr,
                                               const float* __restrict__ pt,
                                               float* __restrict__ ew) {
    int t = blockIdx.x * 256 + threadIdx.x;      // 65536 = B*N*K
    int bn = t >> 4;
    int b  = bn >> 7;
    float2 ci = *(const float2*)(centre + (size_t)bn * 2);
    int j = nidx[t];
    float2 cj = *(const float2*)(centre + (size_t)(b * N_ + j) * 2);
    float cx = ci.x - cj.x, cy = ci.y - cj.y;
    float rho = sqrtf(cx * cx + cy * cy);
    float theta = atan2f(cx, cy);                // NOTE: atan2(x, y) per reference
    float w[KER];
    float sum = 0.f;
#pragma unroll
    for (int m = 0; m < KER; ++m) {
        float dr = rho - mr[m];
        float wr = expf(-0.5f * dr * dr / (1e-14f + pr[m] * pr[m]));
        float a1 = fabsf(theta - mt[m]);
        float a2 = fabsf(6.2831853071795864f - a1);
        float am = fminf(a1, a2);
        float wt = expf(-0.5f * am * am / (1e-14f + pt[m] * pt[m]));
        float wv = wr * wt;
        if (isnan(wv)) wv = 0.f;
        w[m] = wv;
        sum += wv;
    }
    float scale = gw[t] / sum;
#pragma unroll
    for (int m = 0; m < KER; ++m) ew[(size_t)t * KER + m] = w[m] * scale;
}

// ---------------------------------------------------------------------------
// Kernel 4: GEMM  G[4096][1024] (f32) = Fb[4096][1024] x WbT[1024][1024]^T
//           (dot over c;  G[r][o] = sum_c Fb[r][c] * WbT[o][c])
// 128x128 tile, BK=32, 4 waves (2x2), 16x16x32 bf16 MFMA
// ---------------------------------------------------------------------------
__global__ __launch_bounds__(256) void k_gemm(const ushort* __restrict__ Fb,
                                              const ushort* __restrict__ WbT,
                                              float* __restrict__ G) {
    __shared__ ushort As[128 * 32];   // [row][k] row-major, 8 KB
    __shared__ ushort Bs[128 * 32];   // [ocol][k] row-major, 8 KB
    int tid  = threadIdx.x;
    int wave = tid >> 6;
    int lane = tid & 63;
    int wm = wave >> 1, wn = wave & 1;
    int bm = blockIdx.x * 128;
    int bn = blockIdx.y * 128;
    int lr = lane & 15;       // fragment row/col
    int kg = lane >> 4;       // k-group (0..3)

    f32x4 acc[4][4];
#pragma unroll
    for (int i = 0; i < 4; ++i)
#pragma unroll
        for (int j = 0; j < 4; ++j) acc[i][j] = (f32x4){0.f, 0.f, 0.f, 0.f};

    for (int kt = 0; kt < C_; kt += 32) {
        __syncthreads();
        // stage A and B tiles: 512 16B segments each; seg s: row=s>>2, kcol=(s&3)*8
#pragma unroll
        for (int i = 0; i < 2; ++i) {
            int sbase = i * 256 + wave * 64;
            int s = sbase + lane;
            int row = s >> 2;
            int kc  = (s & 3) * 8;
            const ushort* ga = Fb + (size_t)(bm + row) * C_ + kt + kc;
            GLOAD_LDS16(ga, As + sbase * 8);
            const ushort* gb = WbT + (size_t)(bn + row) * C_ + kt + kc;
            GLOAD_LDS16(gb, Bs + sbase * 8);
        }
        __syncthreads();

        bf16x8 af[4], bfr[4];
#pragma unroll
        for (int mi = 0; mi < 4; ++mi) {
            int row = wm * 64 + mi * 16 + lr;
            af[mi] = *(const bf16x8*)(As + row * 32 + kg * 8);
        }
#pragma unroll
        for (int ni = 0; ni < 4; ++ni) {
            int orow = wn * 64 + ni * 16 + lr;
            bfr[ni] = *(const bf16x8*)(Bs + orow * 32 + kg * 8);
        }
#pragma unroll
        for (int mi = 0; mi < 4; ++mi)
#pragma unroll
            for (int ni = 0; ni < 4; ++ni)
                acc[mi][ni] = __builtin_amdgcn_mfma_f32_16x16x32_bf16(
                    af[mi], bfr[ni], acc[mi][ni], 0, 0, 0);
    }

    // epilogue: C/D layout col=lane&15, row=(lane>>4)*4+reg  [verified m89]
#pragma unroll
    for (int mi = 0; mi < 4; ++mi)
#pragma unroll
        for (int ni = 0; ni < 4; ++ni)
#pragma unroll
            for (int r = 0; r < 4; ++r) {
                int grow = bm + wm * 64 + mi * 16 + kg * 4 + r;
                int gcol = bn + wn * 64 + ni * 16 + lr;
                G[(size_t)grow * OUTC + gcol] = acc[mi][ni][r];
            }
}

// ---------------------------------------------------------------------------
// Kernel 5: out[b][n][m*128+d] = relu( sum_k ew[b][n][k][m] * G[b*128+idx][m*128+d] )
// ---------------------------------------------------------------------------
__global__ __launch_bounds__(256) void k_gather(const float* __restrict__ G,
                                                const float* __restrict__ ew,
                                                const int* __restrict__ nidx,
                                                float* __restrict__ out) {
    int t = blockIdx.x * 256 + threadIdx.x;   // 4,194,304
    int col = t & (OUTC - 1);
    int bn  = t >> 10;
    int b   = bn >> 7;
    int m   = col >> 7;
    const int*   ip = nidx + (size_t)bn * KNB;
    const float* ep = ew + (size_t)bn * (KNB * KER) + m;
    float s = 0.f;
#pragma unroll
    for (int k = 0; k < KNB; ++k) {
        int j = ip[k];
        s += ep[k * KER] * G[((size_t)(b * N_ + j) << 10) + col];
    }
    out[t] = fmaxf(s, 0.f);
}

// ---------------------------------------------------------------------------
extern "C" void kernel_launch(void* const* d_in, const int* in_sizes, int n_in,
                              void* d_out, int out_size, void* d_ws, size_t ws_size,
                              hipStream_t stream) {
    const float* node_feats      = (const float*)d_in[0];
    const float* node_centre     = (const float*)d_in[1];
    const int*   neighbor_idx    = (const int*)d_in[2];
    const float* graph_weights   = (const float*)d_in[3];
    const float* mean_rho        = (const float*)d_in[4];
    const float* mean_theta      = (const float*)d_in[5];
    const float* precision_rho   = (const float*)d_in[6];
    const float* precision_theta = (const float*)d_in[7];
    const float* conv_w          = (const float*)d_in[8];
    float* out = (float*)d_out;

    char* ws = (char*)d_ws;
    ushort* Fb  = (ushort*)(ws);                   // 8 MB
    ushort* WbT = (ushort*)(ws + (8u  << 20));     // 2 MB
    float*  ew  = (float*) (ws + (10u << 20));     // 2 MB
    float*  G   = (float*) (ws + (12u << 20));     // 16 MB

    k_convert_f  <<<4096, 256, 0, stream>>>(node_feats, Fb);
    k_transpose_w<<<1024, 256, 0, stream>>>(conv_w, WbT);
    k_edgew      <<<256, 256, 0, stream>>>(node_centre, neighbor_idx, graph_weights,
                                           mean_rho, mean_theta,
                                           precision_rho, precision_theta, ew);
    dim3 ggrid(BN_TOT / 128, OUTC / 128);
    k_gemm       <<<ggrid, 256, 0, stream>>>(Fb, WbT, G);
    k_gather     <<<(BN_TOT * OUTC) / 256, 256, 0, stream>>>(G, ew, neighbor_idx, out);
}

// Round 2
// 113.232 us; speedup vs baseline: 1.2382x; 1.2382x over previous
//
#include <hip/hip_runtime.h>
#include <hip/hip_bf16.h>

// Problem constants
#define B_   32
#define N_   128
#define KNB  16
#define C_   1024
#define KER  8
#define DOUT 128      // OUT/KERNEL
#define OUTC 1024
#define BN_TOT (B_ * N_)   // 4096
#define BK   64
#define NT   (C_ / BK)     // 16 K-steps

typedef __attribute__((ext_vector_type(8))) short bf16x8;
typedef __attribute__((ext_vector_type(4))) float f32x4;

__device__ __forceinline__ ushort f2bf(float f) {
    unsigned u = __builtin_bit_cast(unsigned, f);
    unsigned r = (u + 0x7FFFu + ((u >> 16) & 1u)) >> 16;
    return (ushort)r;
}

#define GLOAD_LDS16(gp, lp)                                                    \
    __builtin_amdgcn_global_load_lds(                                          \
        (__attribute__((address_space(1))) void*)(gp),                         \
        (__attribute__((address_space(3))) void*)(lp), 16, 0, 0)

// ---------------------------------------------------------------------------
// Kernel 1: node_feats f32 [4096][1024] -> bf16 Fb [4096][1024]
// ---------------------------------------------------------------------------
__global__ __launch_bounds__(256) void k_convert_f(const float* __restrict__ f,
                                                   ushort* __restrict__ Fb) {
    int t = blockIdx.x * 256 + threadIdx.x;
    float4 v = ((const float4*)f)[t];
    ushort4 o;
    o.x = f2bf(v.x); o.y = f2bf(v.y); o.z = f2bf(v.z); o.w = f2bf(v.w);
    ((ushort4*)Fb)[t] = o;
}

// ---------------------------------------------------------------------------
// Kernel 2: conv_w f32 [KER][C][DOUT] -> WbT bf16 [KER*DOUT][C]
// ---------------------------------------------------------------------------
__global__ __launch_bounds__(256) void k_transpose_w(const float* __restrict__ cw,
                                                     ushort* __restrict__ WbT) {
    __shared__ float tile[32][33];
    int bid = blockIdx.x;            // 8 * 32 * 4 = 1024 blocks
    int dt = bid & 3;
    int ct = (bid >> 2) & 31;
    int m  = bid >> 7;
    int tx = threadIdx.x & 31;
    int ty = threadIdx.x >> 5;
#pragma unroll
    for (int i = 0; i < 4; ++i) {
        int cr = ty + i * 8;
        tile[cr][tx] = cw[((size_t)m * C_ + (ct * 32 + cr)) * DOUT + dt * 32 + tx];
    }
    __syncthreads();
#pragma unroll
    for (int i = 0; i < 4; ++i) {
        int dr = ty + i * 8;
        WbT[((size_t)(m * DOUT + dt * 32 + dr)) * C_ + ct * 32 + tx] = f2bf(tile[tx][dr]);
    }
}

// ---------------------------------------------------------------------------
// Kernel 3: edge weights ew[b][n][k][m] f32
// ---------------------------------------------------------------------------
__global__ __launch_bounds__(256) void k_edgew(const float* __restrict__ centre,
                                               const int* __restrict__ nidx,
                                               const float* __restrict__ gw,
                                               const float* __restrict__ mr,
                                               const float* __restrict__ mt,
                                               const float* __restrict__ pr,
                                               const float* __restrict__ pt,
                                               float* __restrict__ ew) {
    int t = blockIdx.x * 256 + threadIdx.x;      // 65536 = B*N*K
    int bn = t >> 4;
    int b  = bn >> 7;
    float2 ci = *(const float2*)(centre + (size_t)bn * 2);
    int j = nidx[t];
    float2 cj = *(const float2*)(centre + (size_t)(b * N_ + j) * 2);
    float cx = ci.x - cj.x, cy = ci.y - cj.y;
    float rho = sqrtf(cx * cx + cy * cy);
    float theta = atan2f(cx, cy);                // atan2(x, y) per reference
    float w[KER];
    float sum = 0.f;
#pragma unroll
    for (int m = 0; m < KER; ++m) {
        float dr = rho - mr[m];
        float wr = expf(-0.5f * dr * dr / (1e-14f + pr[m] * pr[m]));
        float a1 = fabsf(theta - mt[m]);
        float a2 = fabsf(6.2831853071795864f - a1);
        float am = fminf(a1, a2);
        float wt = expf(-0.5f * am * am / (1e-14f + pt[m] * pt[m]));
        float wv = wr * wt;
        if (isnan(wv)) wv = 0.f;
        w[m] = wv;
        sum += wv;
    }
    float scale = gw[t] / sum;
#pragma unroll
    for (int m = 0; m < KER; ++m) ew[(size_t)t * KER + m] = w[m] * scale;
}

// ---------------------------------------------------------------------------
// Kernel 4 (fused): per block (b, m):
//   Gt[128][128] = Fb_b (128 x 1024) x WbT_m^T  -> LDS
//   out[b][n][m*128+d] = relu( sum_k ew[b][n][k][m] * Gt[j[n][k]][d] )
// 8 waves (2x4 grid, 64x32 per wave), BK=64, double-buffered global_load_lds
// with counted vmcnt (T3/T4-lite). XOR chunk swizzle (both-sides, m201).
// ---------------------------------------------------------------------------
__global__ __launch_bounds__(512) void k_gemm_fused(const ushort* __restrict__ Fb,
                                                    const ushort* __restrict__ WbT,
                                                    const float* __restrict__ ew,
                                                    const int* __restrict__ nidx,
                                                    float* __restrict__ out) {
    // smem union: [staging: 2 bufs x (A 16KB + B 16KB) = 64KB] then reused as
    // Gt f32 [128][132] = 67584 B
    __shared__ __align__(16) char smem[67584];

    int tid  = threadIdx.x;
    int wave = tid >> 6;
    int lane = tid & 63;
    int wm = wave >> 2;            // 0..1 (64-row half)
    int wn = wave & 3;             // 0..3 (32-col quarter)
    int lr = lane & 15;
    int kg = lane >> 4;
    int b = blockIdx.x;            // batch
    int m = blockIdx.y;            // kernel index (=128-col tile)

    const ushort* Abase = Fb  + (size_t)b * N_ * C_;
    const ushort* Bbase = WbT + (size_t)m * DOUT * C_;

    f32x4 acc[4][2];
#pragma unroll
    for (int i = 0; i < 4; ++i)
#pragma unroll
        for (int j = 0; j < 2; ++j) acc[i][j] = (f32x4){0.f, 0.f, 0.f, 0.f};

    // --- staging: tile is [128 rows][64 k] bf16 = 128 B/row = 8 chunks of 16B.
    // Source pre-swizzle: LDS chunk (s&7) of row receives global chunk (s&7)^(row&7).
    auto STAGE = [&](int buf, int kt) {
        ushort* As = (ushort*)(smem + buf * 32768);
        ushort* Bs = (ushort*)(smem + buf * 32768 + 16384);
#pragma unroll
        for (int i = 0; i < 2; ++i) {
            int segb = i * 512 + wave * 64;       // wave-uniform LDS base
            int seg  = segb + lane;
            int row  = seg >> 3;
            int ch   = (seg & 7) ^ (row & 7);
            const ushort* ga = Abase + (size_t)row * C_ + kt * BK + ch * 8;
            GLOAD_LDS16(ga, As + segb * 8);
            const ushort* gb = Bbase + (size_t)row * C_ + kt * BK + ch * 8;
            GLOAD_LDS16(gb, Bs + segb * 8);
        }
    };

    // Precompute fragment byte offsets (within one staging buffer), swizzled read.
    int aoff[4][2], boff[2][2];
#pragma unroll
    for (int mi = 0; mi < 4; ++mi)
#pragma unroll
        for (int kk = 0; kk < 2; ++kk) {
            int row = wm * 64 + mi * 16 + lr;
            int ch  = (kk * 4 + kg) ^ (row & 7);
            aoff[mi][kk] = row * 128 + ch * 16;
        }
#pragma unroll
    for (int ni = 0; ni < 2; ++ni)
#pragma unroll
        for (int kk = 0; kk < 2; ++kk) {
            int row = wn * 32 + ni * 16 + lr;
            int ch  = (kk * 4 + kg) ^ (row & 7);
            boff[ni][kk] = 16384 + row * 128 + ch * 16;
        }

    STAGE(0, 0);
    for (int kt = 0; kt < NT; ++kt) {
        int cur = kt & 1;
        const char* bufp = smem + cur * 32768;
        if (kt + 1 < NT) {
            STAGE(cur ^ 1, kt + 1);               // 4 loads/thread in flight
            asm volatile("s_waitcnt vmcnt(4)" ::: "memory");  // cur tile drained
        } else {
            asm volatile("s_waitcnt vmcnt(0)" ::: "memory");  // drain all
        }
        __builtin_amdgcn_s_barrier();
#pragma unroll
        for (int kk = 0; kk < 2; ++kk) {
            bf16x8 af[4], bv[2];
#pragma unroll
            for (int mi = 0; mi < 4; ++mi)
                af[mi] = *(const bf16x8*)(bufp + aoff[mi][kk]);
#pragma unroll
            for (int ni = 0; ni < 2; ++ni)
                bv[ni] = *(const bf16x8*)(bufp + boff[ni][kk]);
#pragma unroll
            for (int mi = 0; mi < 4; ++mi)
#pragma unroll
                for (int ni = 0; ni < 2; ++ni)
                    acc[mi][ni] = __builtin_amdgcn_mfma_f32_16x16x32_bf16(
                        af[mi], bv[ni], acc[mi][ni], 0, 0, 0);
        }
        asm volatile("" ::: "memory");            // pin LDS reads before barrier
        __builtin_amdgcn_s_barrier();             // reads done -> next STAGE may overwrite
    }

    // --- epilogue: acc -> Gt LDS (f32 [128][132], pad for write-bank spread)
    float* Gt = (float*)smem;                     // reuse (all DMA drained above)
#pragma unroll
    for (int mi = 0; mi < 4; ++mi)
#pragma unroll
        for (int ni = 0; ni < 2; ++ni)
#pragma unroll
            for (int r = 0; r < 4; ++r) {
                int grow = wm * 64 + mi * 16 + kg * 4 + r;   // C/D: row=kg*4+r
                int gcol = wn * 32 + ni * 16 + lr;           //      col=lane&15
                Gt[grow * 132 + gcol] = acc[mi][ni][r];
            }
    __syncthreads();

    // --- gather: thread handles row n = tid>>2, col quarter q = tid&3 (32 cols)
    int n = tid >> 2, q = tid & 3;
    const int*   ip = nidx + (size_t)(b * N_ + n) * KNB;
    const float* ep = ew   + (size_t)(b * N_ + n) * (KNB * KER) + m;
    f32x4 o[8];
#pragma unroll
    for (int i = 0; i < 8; ++i) o[i] = (f32x4){0.f, 0.f, 0.f, 0.f};
#pragma unroll
    for (int k = 0; k < KNB; ++k) {
        int j = ip[k];
        float w = ep[k * KER];
        const float* gr = Gt + j * 132 + q * 32;
#pragma unroll
        for (int i = 0; i < 8; ++i) {
            f32x4 v = *(const f32x4*)(gr + i * 4);
            o[i] += v * w;
        }
    }
    float* op = out + (size_t)(b * N_ + n) * OUTC + m * DOUT + q * 32;
#pragma unroll
    for (int i = 0; i < 8; ++i) {
        f32x4 r = o[i];
#pragma unroll
        for (int jj = 0; jj < 4; ++jj) r[jj] = fmaxf(r[jj], 0.f);
        *(f32x4*)(op + i * 4) = r;
    }
}

// ---------------------------------------------------------------------------
extern "C" void kernel_launch(void* const* d_in, const int* in_sizes, int n_in,
                              void* d_out, int out_size, void* d_ws, size_t ws_size,
                              hipStream_t stream) {
    const float* node_feats      = (const float*)d_in[0];
    const float* node_centre     = (const float*)d_in[1];
    const int*   neighbor_idx    = (const int*)d_in[2];
    const float* graph_weights   = (const float*)d_in[3];
    const float* mean_rho        = (const float*)d_in[4];
    const float* mean_theta      = (const float*)d_in[5];
    const float* precision_rho   = (const float*)d_in[6];
    const float* precision_theta = (const float*)d_in[7];
    const float* conv_w          = (const float*)d_in[8];
    float* out = (float*)d_out;

    char* ws = (char*)d_ws;
    ushort* Fb  = (ushort*)(ws);                   // 8 MB
    ushort* WbT = (ushort*)(ws + (8u  << 20));     // 2 MB
    float*  ew  = (float*) (ws + (10u << 20));     // 2 MB

    k_convert_f  <<<4096, 256, 0, stream>>>(node_feats, Fb);
    k_transpose_w<<<1024, 256, 0, stream>>>(conv_w, WbT);
    k_edgew      <<<256, 256, 0, stream>>>(node_centre, neighbor_idx, graph_weights,
                                           mean_rho, mean_theta,
                                           precision_rho, precision_theta, ew);
    dim3 ggrid(B_, KER);   // 32 x 8 = 256 blocks, one (batch, kernel) tile each
    k_gemm_fused <<<ggrid, 512, 0, stream>>>(Fb, WbT, ew, neighbor_idx, out);
}

// Round 3
// 110.084 us; speedup vs baseline: 1.2736x; 1.0286x over previous
//
#include <hip/hip_runtime.h>
#include <hip/hip_bf16.h>

// Problem constants
#define B_   32
#define N_   128
#define KNB  16
#define C_   1024
#define KER  8
#define DOUT 128      // OUT/KERNEL
#define OUTC 1024
#define BN_TOT (B_ * N_)   // 4096
#define BK   64
#define NT   (C_ / BK)     // 16 K-steps

typedef __attribute__((ext_vector_type(8))) short bf16x8;
typedef __attribute__((ext_vector_type(4))) float f32x4;

__device__ __forceinline__ ushort f2bf(float f) {
    unsigned u = __builtin_bit_cast(unsigned, f);
    unsigned r = (u + 0x7FFFu + ((u >> 16) & 1u)) >> 16;
    return (ushort)r;
}

#define GLOAD_LDS16(gp, lp)                                                    \
    __builtin_amdgcn_global_load_lds(                                          \
        (__attribute__((address_space(1))) void*)(gp),                         \
        (__attribute__((address_space(3))) void*)(lp), 16, 0, 0)

// ---------------------------------------------------------------------------
// Prep kernel (merged): blocks [0,4096): convert node_feats f32->bf16
//                       blocks [4096,5120): transpose conv_w -> WbT bf16
//                       blocks [5120,5376): edge weights
// ---------------------------------------------------------------------------
__global__ __launch_bounds__(256) void k_prep(const float* __restrict__ f,
                                              ushort* __restrict__ Fb,
                                              const float* __restrict__ cw,
                                              ushort* __restrict__ WbT,
                                              const float* __restrict__ centre,
                                              const int* __restrict__ nidx,
                                              const float* __restrict__ gw,
                                              const float* __restrict__ mr,
                                              const float* __restrict__ mt,
                                              const float* __restrict__ pr,
                                              const float* __restrict__ pt,
                                              float* __restrict__ ew) {
    __shared__ float tile[32][33];
    int bid = blockIdx.x;
    int tid = threadIdx.x;
    if (bid < 4096) {
        // ---- convert: 1M threads x 4 elems
        int t = bid * 256 + tid;
        float4 v = ((const float4*)f)[t];
        ushort4 o;
        o.x = f2bf(v.x); o.y = f2bf(v.y); o.z = f2bf(v.z); o.w = f2bf(v.w);
        ((ushort4*)Fb)[t] = o;
    } else if (bid < 5120) {
        // ---- transpose conv_w [KER][C][DOUT] -> WbT [KER*DOUT][C]
        int b2 = bid - 4096;             // 8 * 32 * 4 = 1024 blocks
        int dt = b2 & 3;
        int ct = (b2 >> 2) & 31;
        int m  = b2 >> 7;
        int tx = tid & 31;
        int ty = tid >> 5;
#pragma unroll
        for (int i = 0; i < 4; ++i) {
            int cr = ty + i * 8;
            tile[cr][tx] = cw[((size_t)m * C_ + (ct * 32 + cr)) * DOUT + dt * 32 + tx];
        }
        __syncthreads();
#pragma unroll
        for (int i = 0; i < 4; ++i) {
            int dr = ty + i * 8;
            WbT[((size_t)(m * DOUT + dt * 32 + dr)) * C_ + ct * 32 + tx] = f2bf(tile[tx][dr]);
        }
    } else {
        // ---- edge weights: 65536 threads = B*N*K
        int t = (bid - 5120) * 256 + tid;
        int bn = t >> 4;
        int b  = bn >> 7;
        float2 ci = *(const float2*)(centre + (size_t)bn * 2);
        int j = nidx[t];
        float2 cj = *(const float2*)(centre + (size_t)(b * N_ + j) * 2);
        float cx = ci.x - cj.x, cy = ci.y - cj.y;
        float rho = sqrtf(cx * cx + cy * cy);
        float theta = atan2f(cx, cy);            // atan2(x, y) per reference
        float w[KER];
        float sum = 0.f;
#pragma unroll
        for (int m = 0; m < KER; ++m) {
            float dr = rho - mr[m];
            float wr = expf(-0.5f * dr * dr / (1e-14f + pr[m] * pr[m]));
            float a1 = fabsf(theta - mt[m]);
            float a2 = fabsf(6.2831853071795864f - a1);
            float am = fminf(a1, a2);
            float wt = expf(-0.5f * am * am / (1e-14f + pt[m] * pt[m]));
            float wv = wr * wt;
            if (isnan(wv)) wv = 0.f;
            w[m] = wv;
            sum += wv;
        }
        float scale = gw[t] / sum;
#pragma unroll
        for (int m = 0; m < KER; ++m) ew[(size_t)t * KER + m] = w[m] * scale;
    }
}

// ---------------------------------------------------------------------------
// Fused kernel: per block (b, m):
//   Gt[128][128] = Fb_b (128 x 1024) x WbT_m^T  (bf16 MFMA, f32 acc) -> LDS
//   out[b][n][m*128+d] = relu( sum_k ew[b][n][k][m] * Gt[j[n][k]][d] )
// 8 waves (2x4), BK=64, DEPTH-3 pipelined global_load_lds, counted vmcnt.
// XOR chunk swizzle on staging (both-sides, m201 pattern).
// ---------------------------------------------------------------------------
__global__ __launch_bounds__(512) void k_gemm_fused(const ushort* __restrict__ Fb,
                                                    const ushort* __restrict__ WbT,
                                                    const float* __restrict__ ew,
                                                    const int* __restrict__ nidx,
                                                    float* __restrict__ out) {
    // 3 staging buffers x 32 KB = 96 KB; Gt f32 [128][132] = 67584 B unions in.
    __shared__ __align__(16) char smem[98304];

    int tid  = threadIdx.x;
    int wave = tid >> 6;
    int lane = tid & 63;
    int wm = wave >> 2;            // 0..1 (64-row half)
    int wn = wave & 3;             // 0..3 (32-col quarter)
    int lr = lane & 15;
    int kg = lane >> 4;
    int b = blockIdx.x;            // batch
    int m = blockIdx.y;            // kernel index (=128-col tile)

    const ushort* Abase = Fb  + (size_t)b * N_ * C_;
    const ushort* Bbase = WbT + (size_t)m * DOUT * C_;

    f32x4 acc[4][2];
#pragma unroll
    for (int i = 0; i < 4; ++i)
#pragma unroll
        for (int j = 0; j < 2; ++j) acc[i][j] = (f32x4){0.f, 0.f, 0.f, 0.f};

    // staging: tile [128 rows][64 k] bf16 = 8 chunks of 16B per row.
    // LDS chunk (s&7) of row receives global chunk (s&7)^(row&7).
    auto STAGE = [&](int buf, int kt) {
        ushort* As = (ushort*)(smem + buf * 32768);
        ushort* Bs = (ushort*)(smem + buf * 32768 + 16384);
#pragma unroll
        for (int i = 0; i < 2; ++i) {
            int segb = i * 512 + wave * 64;       // wave-uniform LDS base
            int seg  = segb + lane;
            int row  = seg >> 3;
            int ch   = (seg & 7) ^ (row & 7);
            const ushort* ga = Abase + (size_t)row * C_ + kt * BK + ch * 8;
            GLOAD_LDS16(ga, As + segb * 8);
            const ushort* gb = Bbase + (size_t)row * C_ + kt * BK + ch * 8;
            GLOAD_LDS16(gb, Bs + segb * 8);
        }
    };

    // fragment byte offsets (buffer-relative), swizzled read side
    int aoff[4][2], boff[2][2];
#pragma unroll
    for (int mi = 0; mi < 4; ++mi)
#pragma unroll
        for (int kk = 0; kk < 2; ++kk) {
            int row = wm * 64 + mi * 16 + lr;
            int ch  = (kk * 4 + kg) ^ (row & 7);
            aoff[mi][kk] = row * 128 + ch * 16;
        }
#pragma unroll
    for (int ni = 0; ni < 2; ++ni)
#pragma unroll
        for (int kk = 0; kk < 2; ++kk) {
            int row = wn * 32 + ni * 16 + lr;
            int ch  = (kk * 4 + kg) ^ (row & 7);
            boff[ni][kk] = 16384 + row * 128 + ch * 16;
        }

    STAGE(0, 0);
    STAGE(1, 1);
    for (int kt = 0; kt < NT; ++kt) {
        int cur = kt % 3;
        const char* bufp = smem + cur * 32768;
        if (kt + 2 < NT) {
            STAGE((kt + 2) % 3, kt + 2);          // 12 loads in flight after issue
            asm volatile("s_waitcnt vmcnt(8)" ::: "memory");   // drain tile kt
        } else if (kt + 1 < NT) {
            asm volatile("s_waitcnt vmcnt(4)" ::: "memory");   // drain tile kt
        } else {
            asm volatile("s_waitcnt vmcnt(0)" ::: "memory");   // drain all
        }
        __builtin_amdgcn_s_barrier();
#pragma unroll
        for (int kk = 0; kk < 2; ++kk) {
            bf16x8 af[4], bv[2];
#pragma unroll
            for (int mi = 0; mi < 4; ++mi)
                af[mi] = *(const bf16x8*)(bufp + aoff[mi][kk]);
#pragma unroll
            for (int ni = 0; ni < 2; ++ni)
                bv[ni] = *(const bf16x8*)(bufp + boff[ni][kk]);
#pragma unroll
            for (int mi = 0; mi < 4; ++mi)
#pragma unroll
                for (int ni = 0; ni < 2; ++ni)
                    acc[mi][ni] = __builtin_amdgcn_mfma_f32_16x16x32_bf16(
                        af[mi], bv[ni], acc[mi][ni], 0, 0, 0);
        }
        asm volatile("" ::: "memory");            // pin LDS reads before barrier
        __builtin_amdgcn_s_barrier();             // reads done -> STAGE may overwrite
    }

    // --- epilogue: acc -> Gt LDS (f32 [128][132])
    float* Gt = (float*)smem;                     // reuse (all DMA drained)
#pragma unroll
    for (int mi = 0; mi < 4; ++mi)
#pragma unroll
        for (int ni = 0; ni < 2; ++ni)
#pragma unroll
            for (int r = 0; r < 4; ++r) {
                int grow = wm * 64 + mi * 16 + kg * 4 + r;   // C/D: row=kg*4+r
                int gcol = wn * 32 + ni * 16 + lr;           //      col=lane&15
                Gt[grow * 132 + gcol] = acc[mi][ni][r];
            }
    __syncthreads();

    // --- gather: thread = (row n = tid>>2, quarter q = tid&3, 32 cols)
    // per-q cyclic rotation within the quarter: bank(i) = (4j + (q*4+i*4+e)&31)%32
    // -> the 4 q-lanes of a row hit 4 distinct banks (conflict-free).
    int n = tid >> 2, q = tid & 3;
    const int*   ip = nidx + (size_t)(b * N_ + n) * KNB;
    const float* ep = ew   + (size_t)(b * N_ + n) * (KNB * KER) + m;
    int rot[8];
#pragma unroll
    for (int i = 0; i < 8; ++i) rot[i] = (q * 4 + i * 4) & 31;
    f32x4 o[8];
#pragma unroll
    for (int i = 0; i < 8; ++i) o[i] = (f32x4){0.f, 0.f, 0.f, 0.f};
#pragma unroll
    for (int k = 0; k < KNB; ++k) {
        int j = ip[k];
        float w = ep[k * KER];
        const float* gr = Gt + j * 132 + q * 32;
#pragma unroll
        for (int i = 0; i < 8; ++i) {
            f32x4 v = *(const f32x4*)(gr + rot[i]);
            o[i] += v * w;
        }
    }
    float* op = out + (size_t)(b * N_ + n) * OUTC + m * DOUT + q * 32;
#pragma unroll
    for (int i = 0; i < 8; ++i) {
        f32x4 r = o[i];
#pragma unroll
        for (int jj = 0; jj < 4; ++jj) r[jj] = fmaxf(r[jj], 0.f);
        *(f32x4*)(op + rot[i]) = r;
    }
}

// ---------------------------------------------------------------------------
extern "C" void kernel_launch(void* const* d_in, const int* in_sizes, int n_in,
                              void* d_out, int out_size, void* d_ws, size_t ws_size,
                              hipStream_t stream) {
    const float* node_feats      = (const float*)d_in[0];
    const float* node_centre     = (const float*)d_in[1];
    const int*   neighbor_idx    = (const int*)d_in[2];
    const float* graph_weights   = (const float*)d_in[3];
    const float* mean_rho        = (const float*)d_in[4];
    const float* mean_theta      = (const float*)d_in[5];
    const float* precision_rho   = (const float*)d_in[6];
    const float* precision_theta = (const float*)d_in[7];
    const float* conv_w          = (const float*)d_in[8];
    float* out = (float*)d_out;

    char* ws = (char*)d_ws;
    ushort* Fb  = (ushort*)(ws);                   // 8 MB
    ushort* WbT = (ushort*)(ws + (8u  << 20));     // 2 MB
    float*  ew  = (float*) (ws + (10u << 20));     // 2 MB

    k_prep<<<5376, 256, 0, stream>>>(node_feats, Fb, conv_w, WbT,
                                     node_centre, neighbor_idx, graph_weights,
                                     mean_rho, mean_theta,
                                     precision_rho, precision_theta, ew);
    dim3 ggrid(B_, KER);   // 32 x 8 = 256 blocks, one (batch, kernel) tile each
    k_gemm_fused<<<ggrid, 512, 0, stream>>>(Fb, WbT, ew, neighbor_idx, out);
}

// Round 4
// 109.102 us; speedup vs baseline: 1.2851x; 1.0090x over previous
//
#include <hip/hip_runtime.h>
#include <hip/hip_bf16.h>

// Problem constants
#define B_   32
#define N_   128
#define KNB  16
#define C_   1024
#define KER  8
#define DOUT 128      // OUT/KERNEL
#define OUTC 1024
#define BK   64
#define NT   (C_ / BK)     // 16 K-steps

typedef __attribute__((ext_vector_type(8))) short bf16x8;
typedef __attribute__((ext_vector_type(4))) float f32x4;

__device__ __forceinline__ ushort f2bf(float f) {
    unsigned u = __builtin_bit_cast(unsigned, f);
    unsigned r = (u + 0x7FFFu + ((u >> 16) & 1u)) >> 16;
    return (ushort)r;
}

#define GLOAD_LDS16(gp, lp)                                                    \
    __builtin_amdgcn_global_load_lds(                                          \
        (__attribute__((address_space(1))) void*)(gp),                         \
        (__attribute__((address_space(3))) void*)(lp), 16, 0, 0)

// ---------------------------------------------------------------------------
// Prep kernel: blocks [0,1024): transpose conv_w [KER][C][DOUT] -> WbT bf16
//              blocks [1024,1280): edge weights ew[b][n][k][m]
// ---------------------------------------------------------------------------
__global__ __launch_bounds__(256) void k_prep(const float* __restrict__ cw,
                                              ushort* __restrict__ WbT,
                                              const float* __restrict__ centre,
                                              const int* __restrict__ nidx,
                                              const float* __restrict__ gw,
                                              const float* __restrict__ mr,
                                              const float* __restrict__ mt,
                                              const float* __restrict__ pr,
                                              const float* __restrict__ pt,
                                              float* __restrict__ ew) {
    __shared__ float tile[32][33];
    int bid = blockIdx.x;
    int tid = threadIdx.x;
    if (bid < 1024) {
        int dt = bid & 3;
        int ct = (bid >> 2) & 31;
        int m  = bid >> 7;
        int tx = tid & 31;
        int ty = tid >> 5;
#pragma unroll
        for (int i = 0; i < 4; ++i) {
            int cr = ty + i * 8;
            tile[cr][tx] = cw[((size_t)m * C_ + (ct * 32 + cr)) * DOUT + dt * 32 + tx];
        }
        __syncthreads();
#pragma unroll
        for (int i = 0; i < 4; ++i) {
            int dr = ty + i * 8;
            WbT[((size_t)(m * DOUT + dt * 32 + dr)) * C_ + ct * 32 + tx] = f2bf(tile[tx][dr]);
        }
    } else {
        int t = (bid - 1024) * 256 + tid;        // 65536 = B*N*K
        int bn = t >> 4;
        int b  = bn >> 7;
        float2 ci = *(const float2*)(centre + (size_t)bn * 2);
        int j = nidx[t];
        float2 cj = *(const float2*)(centre + (size_t)(b * N_ + j) * 2);
        float cx = ci.x - cj.x, cy = ci.y - cj.y;
        float rho = sqrtf(cx * cx + cy * cy);
        float theta = atan2f(cx, cy);            // atan2(x, y) per reference
        float w[KER];
        float sum = 0.f;
#pragma unroll
        for (int m = 0; m < KER; ++m) {
            float dr = rho - mr[m];
            float wr = expf(-0.5f * dr * dr / (1e-14f + pr[m] * pr[m]));
            float a1 = fabsf(theta - mt[m]);
            float a2 = fabsf(6.2831853071795864f - a1);
            float am = fminf(a1, a2);
            float wt = expf(-0.5f * am * am / (1e-14f + pt[m] * pt[m]));
            float wv = wr * wt;
            if (isnan(wv)) wv = 0.f;
            w[m] = wv;
            sum += wv;
        }
        float scale = gw[t] / sum;
#pragma unroll
        for (int m = 0; m < KER; ++m) ew[(size_t)t * KER + m] = w[m] * scale;
    }
}

// ---------------------------------------------------------------------------
// Fused kernel, block (b,m):
//   Gt[128][128] = f32(Fb_b) x WbT_m^T   (A converted f32->bf16 in-kernel)
//   out[b][n][m*128+d] = relu( sum_k ew[b][n][k][m] * Gt[j[n][k]][d] )
// 8 waves (2x4). A: reg-staged (T14 issue-early), B: global_load_lds.
// Double-buffered, ONE barrier per K-step, counted vmcnt(4).
// XOR chunk swizzle on LDS tiles (write-side for A, source-side for B).
// ---------------------------------------------------------------------------
__global__ __launch_bounds__(512) void k_fused(const float* __restrict__ F,
                                               const ushort* __restrict__ WbT,
                                               const float* __restrict__ ew,
                                               const int* __restrict__ nidx,
                                               float* __restrict__ out) {
    // staging: 2 bufs x (A 16KB + B 16KB) = 64KB; Gt f32 [128][132] = 67584 B
    __shared__ __align__(16) char smem[67584];

    int tid  = threadIdx.x;
    int wave = tid >> 6;
    int lane = tid & 63;
    int wm = wave >> 2;            // 0..1 (64-row half)
    int wn = wave & 3;             // 0..3 (32-col quarter)
    int lr = lane & 15;
    int kg = lane >> 4;
    int b = blockIdx.x;
    int m = blockIdx.y;

    const float*  Af = F   + (size_t)b * N_ * C_;
    const ushort* Bb = WbT + (size_t)m * DOUT * C_;

    // A reg-stage mapping: row = tid>>2, 16-col quarter qq = tid&3
    int arow = tid >> 2, qq = tid & 3;
    const float* asrc = Af + (size_t)arow * C_ + qq * 16;
    int as0 = ((qq * 2)     ^ (arow & 7)) * 8 + arow * 64;   // ushort offsets
    int as1 = ((qq * 2 + 1) ^ (arow & 7)) * 8 + arow * 64;

    f32x4 acc[4][2];
#pragma unroll
    for (int i = 0; i < 4; ++i)
#pragma unroll
        for (int j = 0; j < 2; ++j) acc[i][j] = (f32x4){0.f, 0.f, 0.f, 0.f};

    f32x4 areg[4];

    // fragment byte offsets (buffer-relative), swizzled read side
    int aoff[4][2], boff[2][2];
#pragma unroll
    for (int mi = 0; mi < 4; ++mi)
#pragma unroll
        for (int kk = 0; kk < 2; ++kk) {
            int row = wm * 64 + mi * 16 + lr;
            int ch  = (kk * 4 + kg) ^ (row & 7);
            aoff[mi][kk] = row * 128 + ch * 16;
        }
#pragma unroll
    for (int ni = 0; ni < 2; ++ni)
#pragma unroll
        for (int kk = 0; kk < 2; ++kk) {
            int row = wn * 32 + ni * 16 + lr;
            int ch  = (kk * 4 + kg) ^ (row & 7);
            boff[ni][kk] = 16384 + row * 128 + ch * 16;
        }

    auto A_ISSUE = [&](int kt) {
#pragma unroll
        for (int i = 0; i < 4; ++i)
            areg[i] = *(const f32x4*)(asrc + kt * BK + i * 4);
    };
    auto A_WRITE = [&](int buf) {
        ushort* As = (ushort*)(smem + buf * 32768);
        bf16x8 w0, w1;
#pragma unroll
        for (int i = 0; i < 2; ++i)
#pragma unroll
            for (int j = 0; j < 4; ++j) w0[i * 4 + j] = (short)f2bf(areg[i][j]);
#pragma unroll
        for (int i = 0; i < 2; ++i)
#pragma unroll
            for (int j = 0; j < 4; ++j) w1[i * 4 + j] = (short)f2bf(areg[2 + i][j]);
        *(bf16x8*)(As + as0) = w0;
        *(bf16x8*)(As + as1) = w1;
    };
    auto B_ISSUE = [&](int buf, int kt) {
        ushort* Bs = (ushort*)(smem + buf * 32768 + 16384);
#pragma unroll
        for (int i = 0; i < 2; ++i) {
            int segb = i * 512 + wave * 64;       // wave-uniform LDS base
            int seg  = segb + lane;
            int row  = seg >> 3;
            int ch   = (seg & 7) ^ (row & 7);
            const ushort* gb = Bb + (size_t)row * C_ + kt * BK + ch * 8;
            GLOAD_LDS16(gb, Bs + segb * 8);
        }
    };

    // ---- prologue
    A_ISSUE(0);                   // A(0) -> regs
    B_ISSUE(0, 0);                // B(0) in flight (2)
    A_WRITE(0);                   // consumes A(0) (compiler waits; B(0) kept)
    A_ISSUE(1);                   // A(1) in flight (4)
    asm volatile("s_waitcnt vmcnt(4)" ::: "memory");    // drain B(0), keep A(1)
    asm volatile("s_waitcnt lgkmcnt(0)" ::: "memory");  // A(0) writes visible
    __builtin_amdgcn_s_barrier();

    for (int kt = 0; kt < NT; ++kt) {
        int cur = kt & 1;
        const char* bufp = smem + cur * 32768;
        if (kt + 1 < NT) {
            A_WRITE(cur ^ 1);          // A(kt+1) regs -> LDS (other buf)
            B_ISSUE(cur ^ 1, kt + 1);  // B(kt+1) in flight (2, oldest)
        }
        if (kt + 2 < NT) A_ISSUE(kt + 2);   // A(kt+2) in flight (4, youngest)

#pragma unroll
        for (int kk = 0; kk < 2; ++kk) {
            bf16x8 af[4], bv[2];
#pragma unroll
            for (int mi = 0; mi < 4; ++mi)
                af[mi] = *(const bf16x8*)(bufp + aoff[mi][kk]);
#pragma unroll
            for (int ni = 0; ni < 2; ++ni)
                bv[ni] = *(const bf16x8*)(bufp + boff[ni][kk]);
#pragma unroll
            for (int mi = 0; mi < 4; ++mi)
#pragma unroll
                for (int ni = 0; ni < 2; ++ni)
                    acc[mi][ni] = __builtin_amdgcn_mfma_f32_16x16x32_bf16(
                        af[mi], bv[ni], acc[mi][ni], 0, 0, 0);
        }

        if (kt + 1 < NT) {
            if (kt + 2 < NT)
                asm volatile("s_waitcnt vmcnt(4)" ::: "memory");  // drain B(kt+1)
            else
                asm volatile("s_waitcnt vmcnt(0)" ::: "memory");  // tail drain
            asm volatile("s_waitcnt lgkmcnt(0)" ::: "memory");    // A writes visible
            __builtin_amdgcn_s_barrier();
        }
    }

    // ---- epilogue: acc -> Gt LDS (f32 [128][132])
    __syncthreads();                              // full drain; staging dead
    float* Gt = (float*)smem;
#pragma unroll
    for (int mi = 0; mi < 4; ++mi)
#pragma unroll
        for (int ni = 0; ni < 2; ++ni)
#pragma unroll
            for (int r = 0; r < 4; ++r) {
                int grow = wm * 64 + mi * 16 + kg * 4 + r;   // C/D: row=kg*4+r
                int gcol = wn * 32 + ni * 16 + lr;           //      col=lane&15
                Gt[grow * 132 + gcol] = acc[mi][ni][r];
            }
    __syncthreads();

    // ---- gather: thread = (row n = tid>>2, quarter q = tid&3)
    // per-q rotation keeps the 4 q-lanes of a row on distinct banks.
    int n = tid >> 2, q = tid & 3;
    const int*   ip = nidx + (size_t)(b * N_ + n) * KNB;
    const float* ep = ew   + (size_t)(b * N_ + n) * (KNB * KER) + m;
    int rot[8];
#pragma unroll
    for (int i = 0; i < 8; ++i) rot[i] = (q * 4 + i * 4) & 31;
    f32x4 o[8];
#pragma unroll
    for (int i = 0; i < 8; ++i) o[i] = (f32x4){0.f, 0.f, 0.f, 0.f};
#pragma unroll
    for (int k = 0; k < KNB; ++k) {
        int j = ip[k];
        float w = ep[k * KER];
        const float* gr = Gt + j * 132 + q * 32;
#pragma unroll
        for (int i = 0; i < 8; ++i) {
            f32x4 v = *(const f32x4*)(gr + rot[i]);
            o[i] += v * w;
        }
    }
    float* op = out + (size_t)(b * N_ + n) * OUTC + m * DOUT + q * 32;
#pragma unroll
    for (int i = 0; i < 8; ++i) {
        f32x4 r = o[i];
#pragma unroll
        for (int jj = 0; jj < 4; ++jj) r[jj] = fmaxf(r[jj], 0.f);
        *(f32x4*)(op + rot[i]) = r;
    }
}

// ---------------------------------------------------------------------------
extern "C" void kernel_launch(void* const* d_in, const int* in_sizes, int n_in,
                              void* d_out, int out_size, void* d_ws, size_t ws_size,
                              hipStream_t stream) {
    const float* node_feats      = (const float*)d_in[0];
    const float* node_centre     = (const float*)d_in[1];
    const int*   neighbor_idx    = (const int*)d_in[2];
    const float* graph_weights   = (const float*)d_in[3];
    const float* mean_rho        = (const float*)d_in[4];
    const float* mean_theta      = (const float*)d_in[5];
    const float* precision_rho   = (const float*)d_in[6];
    const float* precision_theta = (const float*)d_in[7];
    const float* conv_w          = (const float*)d_in[8];
    float* out = (float*)d_out;

    char* ws = (char*)d_ws;
    ushort* WbT = (ushort*)(ws);                   // 2 MB
    float*  ew  = (float*) (ws + (2u << 20));      // 2 MB

    k_prep<<<1280, 256, 0, stream>>>(conv_w, WbT,
                                     node_centre, neighbor_idx, graph_weights,
                                     mean_rho, mean_theta,
                                     precision_rho, precision_theta, ew);
    dim3 ggrid(B_, KER);   // 32 x 8 = 256 blocks, one (batch, kernel) tile each
    k_fused<<<ggrid, 512, 0, stream>>>(node_feats, WbT, ew, neighbor_idx, out);
}